// Round 16
// baseline (369.144 us; speedup 1.0000x reference)
//
#include <hip/hip_runtime.h>
#include <hip/hip_bf16.h>
#include <cstdint>
#include <cstddef>

// ---------------------------------------------------------------------------
// GAT x3 + fused MLP head.
// GEMMs: MFMA bf16 (fp32 accum), 128x128 tile, XOR-swizzled LDS, FUSED alpha
// epilogue. Head: both GEMMs in one kernel. All inter-kernel tensors bf16.
// Aggregation: CSR-by-dst, 2 nodes/wave, 8 edges in flight, INLINE softmax
// numerators (p = exp(lrelu(alpha_s[src]+alpha_d[dst])) computed in-loop;
// no edge_p pass, no erec buffer). CSR build = 2-level bucket sort.
// ---------------------------------------------------------------------------

#define PA_CHUNK 4096
#define BKT_CAP  12288

using short8  = __attribute__((ext_vector_type(8))) short;
using ushort8 = __attribute__((ext_vector_type(8))) unsigned short;
using f32x4   = __attribute__((ext_vector_type(4))) float;

__device__ __forceinline__ ushort f2bf_rne(float f) {
  uint u = __float_as_uint(f);
  u += 0x7FFFu + ((u >> 16) & 1u);
  return (ushort)(u >> 16);
}

__device__ __forceinline__ float lrelu_exp(float e) {
  return __expf((e > 0.f) ? e : 0.2f * e);
}

__device__ __forceinline__ void acc4(float& x0, float& y0, float& x1, float& y1,
                                     float p, uint2 h) {
  x0 = fmaf(p, __uint_as_float(h.x << 16), x0);
  y0 = fmaf(p, __uint_as_float(h.x & 0xFFFF0000u), y0);
  x1 = fmaf(p, __uint_as_float(h.y << 16), x1);
  y1 = fmaf(p, __uint_as_float(h.y & 0xFFFF0000u), y1);
}

// ---------------- Phase A: scatter edges into coarse buckets ----------------
__global__ __launch_bounds__(256) void bucket_scatter_kernel(
    const int* __restrict__ src, const int* __restrict__ dst,
    int* __restrict__ bcount, uint* __restrict__ buckets, int E, int NB) {
  __shared__ int  hist[256];
  __shared__ int  base[256];
  __shared__ uint recs[PA_CHUNK];
  __shared__ ushort rb[PA_CHUNK];
  const int t = threadIdx.x;
  const int e0 = blockIdx.x * PA_CHUNK;
  const int nE = min(PA_CHUNK, E - e0);

  for (int i = t; i < 256; i += 256) hist[i] = 0;
  __syncthreads();
  for (int i = t; i < nE; i += 256) {
    int s = src[e0 + i], d = dst[e0 + i];
    int b = d >> 9;
    recs[i] = ((uint)s << 9) | (uint)(d & 511);
    rb[i] = (ushort)b;
    atomicAdd(&hist[b], 1);
  }
  __syncthreads();
  if (t < NB) base[t] = (hist[t] > 0) ? atomicAdd(&bcount[t], hist[t]) : 0;
  __syncthreads();
  for (int i = t; i < 256; i += 256) hist[i] = 0;
  __syncthreads();
  for (int i = t; i < nE; i += 256) {
    int b = rb[i];
    int r = atomicAdd(&hist[b], 1);
    int pos = base[b] + r;
    if (pos < BKT_CAP) buckets[(size_t)b * BKT_CAP + pos] = recs[i];
  }
}

__global__ __launch_bounds__(256) void scan_buckets_kernel(
    const int* __restrict__ bcount, int* __restrict__ bbase, int NB,
    int* __restrict__ row_ptr, int N, int E) {
  __shared__ int s[256];
  int t = threadIdx.x;
  int x = (t < NB) ? bcount[t] : 0;
  s[t] = x;
  __syncthreads();
  #pragma unroll
  for (int off = 1; off < 256; off <<= 1) {
    int v = (t >= off) ? s[t - off] : 0;
    __syncthreads();
    s[t] += v;
    __syncthreads();
  }
  if (t < NB) bbase[t] = s[t] - x;
  if (t == 0) row_ptr[N] = E;
}

__global__ __launch_bounds__(256) void bucket_sort_kernel(
    const uint* __restrict__ buckets, const int* __restrict__ bcount,
    const int* __restrict__ bbase, int* __restrict__ row_ptr,
    int* __restrict__ src_sorted, int N) {
  const int b = blockIdx.x;
  const int t = threadIdx.x;
  __shared__ int h[512], o[512], c[512];
  __shared__ int wsum[4];
  const int cnt = min(bcount[b], BKT_CAP);
  const int gbase = bbase[b];
  const uint* rec = buckets + (size_t)b * BKT_CAP;

  for (int i = t; i < 512; i += 256) { h[i] = 0; c[i] = 0; }
  __syncthreads();
  for (int i = t; i < cnt; i += 256) atomicAdd(&h[rec[i] & 511], 1);
  __syncthreads();

  int a0 = h[2 * t], a1 = h[2 * t + 1];
  int s2 = a0 + a1;
  int lane = t & 63, w = t >> 6;
  int v = s2;
  #pragma unroll
  for (int off = 1; off < 64; off <<= 1) {
    int u = __shfl_up(v, off, 64);
    if (lane >= off) v += u;
  }
  if (lane == 63) wsum[w] = v;
  __syncthreads();
  int woff = 0;
  for (int i = 0; i < w; ++i) woff += wsum[i];
  int excl = (v - s2) + woff;
  o[2 * t]     = excl;
  o[2 * t + 1] = excl + a0;
  __syncthreads();

  for (int i = t; i < 512; i += 256) {
    int node = (b << 9) + i;
    if (node < N) row_ptr[node] = gbase + o[i];
  }
  for (int i = t; i < cnt; i += 256) {
    uint r = rec[i];
    int d9 = r & 511;
    int rk = atomicAdd(&c[d9], 1);
    src_sorted[gbase + o[d9] + rk] = (int)(r >> 9);
  }
}

// ---------------- weight prep (5 weights + layer-1 vd, one launch) ----------------
__device__ __forceinline__ void wprep_one(const float* __restrict__ W,
                                          ushort* __restrict__ Wt, int TN, int local) {
  int n = local % TN;
  int c = local / TN;
  ushort8 o;
  #pragma unroll
  for (int j = 0; j < 8; ++j) o[j] = f2bf_rne(W[(c * 8 + j) * TN + n]);
  *(ushort8*)(Wt + n * 128 + ((c ^ (n & 7)) * 8)) = o;
}

__global__ __launch_bounds__(256) void wprep_all_kernel(
    const float* __restrict__ W1s, const float* __restrict__ W2,
    const float* __restrict__ W3,  const float* __restrict__ Wl1,
    const float* __restrict__ Wl2,
    ushort* __restrict__ Wt1, ushort* __restrict__ Wt2, ushort* __restrict__ Wt3,
    ushort* __restrict__ Wtl1, ushort* __restrict__ Wtl2,
    const float* __restrict__ Wd, const float* __restrict__ ad_,
    float* __restrict__ vd) {
  if (blockIdx.x < 36) {
    int idx = blockIdx.x * 256 + threadIdx.x;   // 0..9215
    if (idx < 2048)        wprep_one(W1s, Wt1, 128, idx);
    else if (idx < 4096)   wprep_one(W2,  Wt2, 128, idx - 2048);
    else if (idx < 6144)   wprep_one(W3,  Wt3, 128, idx - 4096);
    else if (idx < 8192)   wprep_one(Wl1, Wtl1, 128, idx - 6144);
    else if (idx < 9216)   wprep_one(Wl2, Wtl2, 64, idx - 8192);
  } else {
    int gw = (blockIdx.x - 36) * 4 + (threadIdx.x >> 6);   // 0..127
    int lane = threadIdx.x & 63;
    float2 w0 = ((const float2*)(Wd + gw * 128))[lane];
    float2 a0 = ((const float2*)ad_)[lane];
    float p = w0.x * a0.x + w0.y * a0.y;
    #pragma unroll
    for (int off = 32; off >= 1; off >>= 1) p += __shfl_down(p, off, 64);
    if (lane == 0) vd[gw] = p;
  }
}

// ---------------- MFMA GEMM + fused alpha epilogue (layers 1-3) ----------------
// ALPHA: 1 = alpha_s & alpha_d from C accumulators (shared-W layers);
//        2 = alpha_s from C, alpha_d = x@adv fused into fp32 staging (layer 1).
template <bool ABF16, int ALPHA>
__global__ __launch_bounds__(256) void mfma_gemm_kernel(const void* __restrict__ Av,
                                                        const ushort* __restrict__ Wt,
                                                        void* __restrict__ Cv, int n,
                                                        const float* __restrict__ asv,
                                                        const float* __restrict__ adv,
                                                        float* __restrict__ alpha_s,
                                                        float* __restrict__ alpha_d) {
  constexpr int TN = 128;
  constexpr int FI = 4;
  constexpr int FJ = 4;
  __shared__ char lds[32768 + 32768];
  ushort* sA = (ushort*)lds;
  ushort* sW = (ushort*)(lds + 32768);

  const int t = threadIdx.x;
  const int row0 = blockIdx.x * 128;
  const int lane = t & 63;
  const int wid = t >> 6;
  const int wr = wid >> 1, wc = wid & 1;

  float4 vd0, vd1;
  if constexpr (ALPHA == 2) {
    vd0 = ((const float4*)adv)[(t & 15) * 2];
    vd1 = ((const float4*)adv)[(t & 15) * 2 + 1];
  }

  #pragma unroll
  for (int i = 0; i < 8; ++i) {
    int r = i * 16 + (t >> 4);
    int c = t & 15;
    int gr = row0 + r;
    ushort8 o = 0;
    if (ABF16) {
      const ushort* Ab = (const ushort*)Av;
      if (gr < n) o = *(const ushort8*)(Ab + (size_t)gr * 128 + c * 8);
    } else {
      const float* A = (const float*)Av;
      float4 v0 = make_float4(0.f, 0.f, 0.f, 0.f), v1 = v0;
      if (gr < n) {
        const float4* Ar = (const float4*)(A + (size_t)gr * 128);
        v0 = Ar[c * 2];
        v1 = Ar[c * 2 + 1];
      }
      if constexpr (ALPHA == 2) {
        float pd = v0.x * vd0.x + v0.y * vd0.y + v0.z * vd0.z + v0.w * vd0.w
                 + v1.x * vd1.x + v1.y * vd1.y + v1.z * vd1.z + v1.w * vd1.w;
        pd += __shfl_xor(pd, 1, 64);
        pd += __shfl_xor(pd, 2, 64);
        pd += __shfl_xor(pd, 4, 64);
        pd += __shfl_xor(pd, 8, 64);
        if ((t & 15) == 0 && gr < n) alpha_d[gr] = pd;
      }
      o[0] = f2bf_rne(v0.x); o[1] = f2bf_rne(v0.y); o[2] = f2bf_rne(v0.z); o[3] = f2bf_rne(v0.w);
      o[4] = f2bf_rne(v1.x); o[5] = f2bf_rne(v1.y); o[6] = f2bf_rne(v1.z); o[7] = f2bf_rne(v1.w);
    }
    *(ushort8*)(sA + r * 128 + ((c ^ (r & 7)) * 8)) = o;
  }
  #pragma unroll
  for (int i = 0; i < 8; ++i) {
    int chunk = i * 256 + t;
    *(ushort8*)(sW + chunk * 8) = *(const ushort8*)(Wt + chunk * 8);
  }
  __syncthreads();

  f32x4 acc[FI][FJ] = {};
  const int lm = lane & 15, q = lane >> 4, l7 = lane & 7;

  #pragma unroll
  for (int kk = 0; kk < 4; ++kk) {
    const int cs = kk * 4 + q;
    short8 af[FI], bfr[FJ];
    #pragma unroll
    for (int i = 0; i < FI; ++i) {
      int r = wr * 64 + i * 16 + lm;
      af[i] = *(const short8*)(sA + r * 128 + ((cs ^ l7) * 8));
    }
    #pragma unroll
    for (int j = 0; j < FJ; ++j) {
      int nn = wc * 64 + j * 16 + lm;
      bfr[j] = *(const short8*)(sW + nn * 128 + ((cs ^ l7) * 8));
    }
    #pragma unroll
    for (int i = 0; i < FI; ++i)
      #pragma unroll
      for (int j = 0; j < FJ; ++j)
        acc[i][j] = __builtin_amdgcn_mfma_f32_16x16x32_bf16(af[i], bfr[j], acc[i][j], 0, 0, 0);
  }

  #pragma unroll
  for (int i = 0; i < FI; ++i) {
    #pragma unroll
    for (int j = 0; j < FJ; ++j) {
      int gcol = wc * 64 + j * 16 + lm;
      #pragma unroll
      for (int r = 0; r < 4; ++r) {
        int grow = row0 + wr * 64 + i * 16 + q * 4 + r;
        if (grow < n)
          ((ushort*)Cv)[(size_t)grow * TN + gcol] = f2bf_rne(acc[i][j][r]);
      }
    }
  }

  // ---- fused alpha epilogue (reuses sA region of LDS after sync) ----
  __syncthreads();
  float* srs = (float*)lds;
  float* srd = (float*)lds + 256;
  float asl[FJ], adl[FJ];
  #pragma unroll
  for (int j = 0; j < FJ; ++j) {
    int gcol = wc * 64 + j * 16 + lm;
    asl[j] = asv[gcol];
    if constexpr (ALPHA == 1) adl[j] = adv[gcol];
  }
  #pragma unroll
  for (int i = 0; i < FI; ++i) {
    #pragma unroll
    for (int r = 0; r < 4; ++r) {
      float ps = 0.f, pdp = 0.f;
      #pragma unroll
      for (int j = 0; j < FJ; ++j) {
        ps = fmaf(acc[i][j][r], asl[j], ps);
        if constexpr (ALPHA == 1) pdp = fmaf(acc[i][j][r], adl[j], pdp);
      }
      ps += __shfl_xor(ps, 1, 64); ps += __shfl_xor(ps, 2, 64);
      ps += __shfl_xor(ps, 4, 64); ps += __shfl_xor(ps, 8, 64);
      if constexpr (ALPHA == 1) {
        pdp += __shfl_xor(pdp, 1, 64); pdp += __shfl_xor(pdp, 2, 64);
        pdp += __shfl_xor(pdp, 4, 64); pdp += __shfl_xor(pdp, 8, 64);
      }
      if (lm == 0) {
        int rl = wr * 64 + i * 16 + q * 4 + r;
        srs[rl * 2 + wc] = ps;
        if constexpr (ALPHA == 1) srd[rl * 2 + wc] = pdp;
      }
    }
  }
  __syncthreads();
  if (t < 128) {
    int grow = row0 + t;
    if (grow < n) {
      alpha_s[grow] = srs[t * 2] + srs[t * 2 + 1];
      if constexpr (ALPHA == 1) alpha_d[grow] = srd[t * 2] + srd[t * 2 + 1];
    }
  }
}

// ---------------- fused MLP head: out = relu(Pb@Wl1+bl1)@Wl2+bl2 ----------------
__global__ __launch_bounds__(256) void head_fused_kernel(
    const uint* __restrict__ Pb, const ushort* __restrict__ Wtl1,
    const float* __restrict__ bl1, const ushort* __restrict__ Wtl2,
    const float* __restrict__ bl2, float* __restrict__ out, int n) {
  __shared__ char lds[32768 + 32768];
  ushort* sA = (ushort*)lds;
  ushort* sW = (ushort*)(lds + 32768);
  const int t = threadIdx.x;
  const int row0 = blockIdx.x * 128;
  const int lane = t & 63, wid = t >> 6;
  const int wr = wid >> 1, wc = wid & 1;
  const int lm = lane & 15, q = lane >> 4, l7 = lane & 7;

  #pragma unroll
  for (int i = 0; i < 8; ++i) {
    int r = i * 16 + (t >> 4);
    int c = t & 15;
    int gr = row0 + r;
    ushort8 o = 0;
    if (gr < n) o = *(const ushort8*)((const ushort*)Pb + (size_t)gr * 128 + c * 8);
    *(ushort8*)(sA + r * 128 + ((c ^ (r & 7)) * 8)) = o;
  }
  #pragma unroll
  for (int i = 0; i < 8; ++i) {
    int chunk = i * 256 + t;
    *(ushort8*)(sW + chunk * 8) = *(const ushort8*)(Wtl1 + chunk * 8);
  }
  __syncthreads();

  f32x4 acc[4][4] = {};
  #pragma unroll
  for (int kk = 0; kk < 4; ++kk) {
    const int cs = kk * 4 + q;
    short8 af[4], bfr[4];
    #pragma unroll
    for (int i = 0; i < 4; ++i) {
      int r = wr * 64 + i * 16 + lm;
      af[i] = *(const short8*)(sA + r * 128 + ((cs ^ l7) * 8));
    }
    #pragma unroll
    for (int j = 0; j < 4; ++j) {
      int nn = wc * 64 + j * 16 + lm;
      bfr[j] = *(const short8*)(sW + nn * 128 + ((cs ^ l7) * 8));
    }
    #pragma unroll
    for (int i = 0; i < 4; ++i)
      #pragma unroll
      for (int j = 0; j < 4; ++j)
        acc[i][j] = __builtin_amdgcn_mfma_f32_16x16x32_bf16(af[i], bfr[j], acc[i][j], 0, 0, 0);
  }
  __syncthreads();

  #pragma unroll
  for (int i = 0; i < 4; ++i) {
    #pragma unroll
    for (int j = 0; j < 4; ++j) {
      int col = wc * 64 + j * 16 + lm;
      float bv = bl1[col];
      #pragma unroll
      for (int r = 0; r < 4; ++r) {
        int row = wr * 64 + i * 16 + q * 4 + r;
        float v = fmaxf(acc[i][j][r] + bv, 0.f);
        sA[row * 128 + (((col >> 3) ^ (row & 7)) * 8) + (col & 7)] = f2bf_rne(v);
      }
    }
  }
  #pragma unroll
  for (int i = 0; i < 4; ++i) {
    int chunk = i * 256 + t;
    *(ushort8*)(sW + chunk * 8) = *(const ushort8*)(Wtl2 + chunk * 8);
  }
  __syncthreads();

  f32x4 acc2[4][2] = {};
  #pragma unroll
  for (int kk = 0; kk < 4; ++kk) {
    const int cs = kk * 4 + q;
    short8 af[4], bfr[2];
    #pragma unroll
    for (int i = 0; i < 4; ++i) {
      int r = wr * 64 + i * 16 + lm;
      af[i] = *(const short8*)(sA + r * 128 + ((cs ^ l7) * 8));
    }
    #pragma unroll
    for (int j = 0; j < 2; ++j) {
      int nn = wc * 32 + j * 16 + lm;
      bfr[j] = *(const short8*)(sW + nn * 128 + ((cs ^ l7) * 8));
    }
    #pragma unroll
    for (int i = 0; i < 4; ++i)
      #pragma unroll
      for (int j = 0; j < 2; ++j)
        acc2[i][j] = __builtin_amdgcn_mfma_f32_16x16x32_bf16(af[i], bfr[j], acc2[i][j], 0, 0, 0);
  }
  #pragma unroll
  for (int i = 0; i < 4; ++i) {
    #pragma unroll
    for (int j = 0; j < 2; ++j) {
      int gcol = wc * 32 + j * 16 + lm;
      float bv = bl2[gcol];
      #pragma unroll
      for (int r = 0; r < 4; ++r) {
        int grow = row0 + wr * 64 + i * 16 + q * 4 + r;
        if (grow < n) out[(size_t)grow * 64 + gcol] = acc2[i][j][r] + bv;
      }
    }
  }
}

// ---------------- GAT aggregation: 2 nodes/wave, inline softmax numerators ----------
__global__ void gat_aggregate_kernel(const uint2* __restrict__ hs2,
                                     const int* __restrict__ src_sorted,
                                     const int* __restrict__ row_ptr,
                                     const float* __restrict__ alpha_s,
                                     const float* __restrict__ alpha_d,
                                     const float* __restrict__ bias,
                                     uint2* __restrict__ outb, int n) {
  const int t = threadIdx.x;
  const int pairw = blockIdx.x * 4 + (t >> 6);   // wave index
  const int lane = t & 63;
  const int half = lane >> 5;
  const int sl = lane & 31;
  const int node = pairw * 2 + half;
  const bool active = node < n;
  const int beg = active ? row_ptr[node] : 0;
  const int end = active ? row_ptr[node + 1] : 0;
  const float ad = active ? alpha_d[node] : 0.f;

  float sA = 0.f, sB = 0.f, sC = 0.f, sD = 0.f;
  float Ax0 = 0.f, Ay0 = 0.f, Ax1 = 0.f, Ay1 = 0.f;
  float Bx0 = 0.f, By0 = 0.f, Bx1 = 0.f, By1 = 0.f;
  float Cx0 = 0.f, Cy0 = 0.f, Cx1 = 0.f, Cy1 = 0.f;
  float Dx0 = 0.f, Dy0 = 0.f, Dx1 = 0.f, Dy1 = 0.f;

  int j = beg;
  for (; j + 8 <= end; j += 8) {
    uint4 uA = *(const uint4*)&src_sorted[j];
    uint4 uB = *(const uint4*)&src_sorted[j + 4];
    float e0 = alpha_s[uA.x] + ad, e1 = alpha_s[uA.y] + ad;
    float e2 = alpha_s[uA.z] + ad, e3 = alpha_s[uA.w] + ad;
    float e4 = alpha_s[uB.x] + ad, e5 = alpha_s[uB.y] + ad;
    float e6 = alpha_s[uB.z] + ad, e7 = alpha_s[uB.w] + ad;
    uint2 h0 = hs2[(size_t)uA.x * 32 + sl];
    uint2 h1 = hs2[(size_t)uA.y * 32 + sl];
    uint2 h2 = hs2[(size_t)uA.z * 32 + sl];
    uint2 h3 = hs2[(size_t)uA.w * 32 + sl];
    uint2 h4 = hs2[(size_t)uB.x * 32 + sl];
    uint2 h5 = hs2[(size_t)uB.y * 32 + sl];
    uint2 h6 = hs2[(size_t)uB.z * 32 + sl];
    uint2 h7 = hs2[(size_t)uB.w * 32 + sl];
    float p0 = lrelu_exp(e0), p1 = lrelu_exp(e1);
    float p2 = lrelu_exp(e2), p3 = lrelu_exp(e3);
    float p4 = lrelu_exp(e4), p5 = lrelu_exp(e5);
    float p6 = lrelu_exp(e6), p7 = lrelu_exp(e7);
    sA += p0 + p1; sB += p2 + p3; sC += p4 + p5; sD += p6 + p7;
    acc4(Ax0, Ay0, Ax1, Ay1, p0, h0);
    acc4(Bx0, By0, Bx1, By1, p1, h1);
    acc4(Cx0, Cy0, Cx1, Cy1, p2, h2);
    acc4(Dx0, Dy0, Dx1, Dy1, p3, h3);
    acc4(Ax0, Ay0, Ax1, Ay1, p4, h4);
    acc4(Bx0, By0, Bx1, By1, p5, h5);
    acc4(Cx0, Cy0, Cx1, Cy1, p6, h6);
    acc4(Dx0, Dy0, Dx1, Dy1, p7, h7);
  }
  for (; j + 4 <= end; j += 4) {
    uint4 uA = *(const uint4*)&src_sorted[j];
    float e0 = alpha_s[uA.x] + ad, e1 = alpha_s[uA.y] + ad;
    float e2 = alpha_s[uA.z] + ad, e3 = alpha_s[uA.w] + ad;
    uint2 h0 = hs2[(size_t)uA.x * 32 + sl];
    uint2 h1 = hs2[(size_t)uA.y * 32 + sl];
    uint2 h2 = hs2[(size_t)uA.z * 32 + sl];
    uint2 h3 = hs2[(size_t)uA.w * 32 + sl];
    float p0 = lrelu_exp(e0), p1 = lrelu_exp(e1);
    float p2 = lrelu_exp(e2), p3 = lrelu_exp(e3);
    sA += p0 + p1; sB += p2 + p3;
    acc4(Ax0, Ay0, Ax1, Ay1, p0, h0);
    acc4(Bx0, By0, Bx1, By1, p1, h1);
    acc4(Cx0, Cy0, Cx1, Cy1, p2, h2);
    acc4(Dx0, Dy0, Dx1, Dy1, p3, h3);
  }
  for (; j < end; ++j) {
    uint u = (uint)src_sorted[j];
    float p = lrelu_exp(alpha_s[u] + ad);
    uint2 h = hs2[(size_t)u * 32 + sl];
    sA += p;
    acc4(Ax0, Ay0, Ax1, Ay1, p, h);
  }

  if (active) {
    float s = (sA + sB) + (sC + sD);
    float inv = 1.f / (s + 1e-16f);
    float4 bv = ((const float4*)bias)[sl];
    float o0 = fmaxf(fmaf((Ax0 + Bx0) + (Cx0 + Dx0), inv, bv.x), 0.f);
    float o1 = fmaxf(fmaf((Ay0 + By0) + (Cy0 + Dy0), inv, bv.y), 0.f);
    float o2 = fmaxf(fmaf((Ax1 + Bx1) + (Cx1 + Dx1), inv, bv.z), 0.f);
    float o3 = fmaxf(fmaf((Ay1 + By1) + (Cy1 + Dy1), inv, bv.w), 0.f);
    uint2 pk;
    pk.x = ((uint)f2bf_rne(o1) << 16) | (uint)f2bf_rne(o0);
    pk.y = ((uint)f2bf_rne(o3) << 16) | (uint)f2bf_rne(o2);
    outb[(size_t)node * 32 + sl] = pk;
  }
}

// ---------------------------------------------------------------------------
extern "C" void kernel_launch(void* const* d_in, const int* in_sizes, int n_in,
                              void* d_out, int out_size, void* d_ws, size_t ws_size,
                              hipStream_t stream) {
  const float* x     = (const float*)d_in[0];
  const int*   eidx  = (const int*)d_in[1];
  const float* W1s   = (const float*)d_in[2];
  const float* W1d   = (const float*)d_in[3];
  const float* a1s   = (const float*)d_in[4];
  const float* a1d   = (const float*)d_in[5];
  const float* b1    = (const float*)d_in[6];
  const float* W2    = (const float*)d_in[7];
  const float* a2s   = (const float*)d_in[8];
  const float* a2d   = (const float*)d_in[9];
  const float* b2    = (const float*)d_in[10];
  const float* W3    = (const float*)d_in[11];
  const float* a3s   = (const float*)d_in[12];
  const float* a3d   = (const float*)d_in[13];
  const float* b3    = (const float*)d_in[14];
  const float* Wl1   = (const float*)d_in[15];
  const float* bl1   = (const float*)d_in[16];
  const float* Wl2   = (const float*)d_in[17];
  const float* bl2   = (const float*)d_in[18];
  float* out = (float*)d_out;

  const int N = in_sizes[0] / 128;
  const int E = in_sizes[1] / 2;
  const int* src = eidx;
  const int* dst = eidx + E;
  const int NB = (N + 511) >> 9;

  // ---- workspace layout ----
  char* base = (char*)d_ws;
  size_t off = 0;
  auto alloc = [&](size_t bytes) -> void* {
    void* p = base + off;
    off += (bytes + 511) & ~(size_t)511;
    return p;
  };
  uint*  Pb       = (uint*)alloc((size_t)N * 128 * 2);   // layer io, packed bf16
  uint*  Qb       = (uint*)alloc((size_t)N * 128 * 2);   // messages, packed bf16
  uint*  buckets  = (uint*)alloc((size_t)256 * BKT_CAP * 4);  // dead after CSR build
  float* alpha_s  = (float*)alloc((size_t)N * 4);
  float* alpha_d  = (float*)alloc((size_t)N * 4);
  float* vd       = (float*)alloc(128 * 4);
  int* row_ptr    = (int*)alloc((size_t)(N + 1) * 4);
  int* bcount     = (int*)alloc(256 * 4);
  int* bbase      = (int*)alloc(256 * 4);
  int* src_sorted = (int*)alloc((size_t)E * 4);
  ushort* Wt1     = (ushort*)alloc(128 * 128 * 2);
  ushort* Wt2     = (ushort*)alloc(128 * 128 * 2);
  ushort* Wt3     = (ushort*)alloc(128 * 128 * 2);
  ushort* Wtl1    = (ushort*)alloc(128 * 128 * 2);
  ushort* Wtl2    = (ushort*)alloc(64 * 128 * 2);
  (void)ws_size;

  const int TB = 256;
  const int ggrid = (N + 127) / 128;
  const int pagrid = (E + PA_CHUNK - 1) / PA_CHUNK;
  const int aggrid = (N + 7) / 8;            // 4 waves/block, 2 nodes/wave

  // ---- CSR build ----
  hipMemsetAsync(bcount, 0, 256 * 4, stream);
  bucket_scatter_kernel<<<pagrid, 256, 0, stream>>>(src, dst, bcount, buckets, E, NB);
  scan_buckets_kernel<<<1, 256, 0, stream>>>(bcount, bbase, NB, row_ptr, N, E);
  bucket_sort_kernel<<<NB, 256, 0, stream>>>(buckets, bcount, bbase, row_ptr, src_sorted, N);

  // ---- weight prep + layer-1 vd (one launch) ----
  wprep_all_kernel<<<68, 256, 0, stream>>>(W1s, W2, W3, Wl1, Wl2,
                                           Wt1, Wt2, Wt3, Wtl1, Wtl2,
                                           W1d, a1d, vd);

  // ---- layer 1: x -> Pb ----
  mfma_gemm_kernel<false, 2><<<ggrid, 256, 0, stream>>>(
      x, Wt1, Qb, N, a1s, vd, alpha_s, alpha_d);
  gat_aggregate_kernel<<<aggrid, TB, 0, stream>>>((const uint2*)Qb, src_sorted, row_ptr,
                                                  alpha_s, alpha_d, b1, (uint2*)Pb, N);

  // ---- layer 2: Pb -> Pb ----
  mfma_gemm_kernel<true, 1><<<ggrid, 256, 0, stream>>>(
      Pb, Wt2, Qb, N, a2s, a2d, alpha_s, alpha_d);
  gat_aggregate_kernel<<<aggrid, TB, 0, stream>>>((const uint2*)Qb, src_sorted, row_ptr,
                                                  alpha_s, alpha_d, b2, (uint2*)Pb, N);

  // ---- layer 3: Pb -> Pb ----
  mfma_gemm_kernel<true, 1><<<ggrid, 256, 0, stream>>>(
      Pb, Wt3, Qb, N, a3s, a3d, alpha_s, alpha_d);
  gat_aggregate_kernel<<<aggrid, TB, 0, stream>>>((const uint2*)Qb, src_sorted, row_ptr,
                                                  alpha_s, alpha_d, b3, (uint2*)Pb, N);

  // ---- fused MLP head ----
  head_fused_kernel<<<ggrid, 256, 0, stream>>>(Pb, Wtl1, bl1, Wtl2, bl2, out, N);
}

// Round 17
// 359.954 us; speedup vs baseline: 1.0255x; 1.0255x over previous
//
#include <hip/hip_runtime.h>
#include <hip/hip_bf16.h>
#include <cstdint>
#include <cstddef>

// ---------------------------------------------------------------------------
// GAT x3 + fused MLP head.
// GEMMs: MFMA bf16 (fp32 accum), 128x128 tile, XOR-swizzled LDS, FUSED alpha
// epilogue. Head: both GEMMs in one kernel. All inter-kernel tensors bf16.
// Aggregation: CSR-by-dst, 2 nodes/wave, 8 edges in flight, packed (src,p)
// records (edge_p pass). CSR build = 2-level bucket sort; bucket bases
// computed in-block (no scan dispatch); weight prep rides the scatter grid.
// ---------------------------------------------------------------------------

#define PA_CHUNK 4096
#define BKT_CAP  12288

using short8  = __attribute__((ext_vector_type(8))) short;
using ushort8 = __attribute__((ext_vector_type(8))) unsigned short;
using f32x4   = __attribute__((ext_vector_type(4))) float;

__device__ __forceinline__ ushort f2bf_rne(float f) {
  uint u = __float_as_uint(f);
  u += 0x7FFFu + ((u >> 16) & 1u);
  return (ushort)(u >> 16);
}

__device__ __forceinline__ void acc4(float& x0, float& y0, float& x1, float& y1,
                                     float p, uint2 h) {
  x0 = fmaf(p, __uint_as_float(h.x << 16), x0);
  y0 = fmaf(p, __uint_as_float(h.x & 0xFFFF0000u), y0);
  x1 = fmaf(p, __uint_as_float(h.y << 16), x1);
  y1 = fmaf(p, __uint_as_float(h.y & 0xFFFF0000u), y1);
}

__device__ __forceinline__ void wprep_one(const float* __restrict__ W,
                                          ushort* __restrict__ Wt, int TN, int local) {
  int n = local % TN;
  int c = local / TN;
  ushort8 o;
  #pragma unroll
  for (int j = 0; j < 8; ++j) o[j] = f2bf_rne(W[(c * 8 + j) * TN + n]);
  *(ushort8*)(Wt + n * 128 + ((c ^ (n & 7)) * 8)) = o;
}

// ---------------- Phase A: edge scatter + weight prep on one grid ----------------
__global__ __launch_bounds__(256) void bucket_scatter_kernel(
    const int* __restrict__ src, const int* __restrict__ dst,
    int* __restrict__ bcount, uint* __restrict__ buckets, int E, int NB, int pagrid,
    const float* __restrict__ W1s, const float* __restrict__ W2,
    const float* __restrict__ W3,  const float* __restrict__ Wl1,
    const float* __restrict__ Wl2,
    ushort* __restrict__ Wt1, ushort* __restrict__ Wt2, ushort* __restrict__ Wt3,
    ushort* __restrict__ Wtl1, ushort* __restrict__ Wtl2,
    const float* __restrict__ Wd, const float* __restrict__ ad_,
    float* __restrict__ vd) {
  const int t = threadIdx.x;
  if ((int)blockIdx.x >= pagrid) {
    int xb = blockIdx.x - pagrid;          // 0..67
    if (xb < 36) {
      int idx = xb * 256 + t;              // 0..9215
      if (idx < 2048)        wprep_one(W1s, Wt1, 128, idx);
      else if (idx < 4096)   wprep_one(W2,  Wt2, 128, idx - 2048);
      else if (idx < 6144)   wprep_one(W3,  Wt3, 128, idx - 4096);
      else if (idx < 8192)   wprep_one(Wl1, Wtl1, 128, idx - 6144);
      else if (idx < 9216)   wprep_one(Wl2, Wtl2, 64, idx - 8192);
    } else {
      int gw = (xb - 36) * 4 + (t >> 6);   // 0..127
      int lane = t & 63;
      float2 w0 = ((const float2*)(Wd + gw * 128))[lane];
      float2 a0 = ((const float2*)ad_)[lane];
      float p = w0.x * a0.x + w0.y * a0.y;
      #pragma unroll
      for (int off = 32; off >= 1; off >>= 1) p += __shfl_down(p, off, 64);
      if (lane == 0) vd[gw] = p;
    }
    return;
  }

  __shared__ int  hist[256];
  __shared__ int  base[256];
  __shared__ uint recs[PA_CHUNK];
  __shared__ ushort rb[PA_CHUNK];
  const int e0 = blockIdx.x * PA_CHUNK;
  const int nE = min(PA_CHUNK, E - e0);

  for (int i = t; i < 256; i += 256) hist[i] = 0;
  __syncthreads();
  for (int i = t; i < nE; i += 256) {
    int s = src[e0 + i], d = dst[e0 + i];
    int b = d >> 9;
    recs[i] = ((uint)s << 9) | (uint)(d & 511);
    rb[i] = (ushort)b;
    atomicAdd(&hist[b], 1);
  }
  __syncthreads();
  if (t < NB) base[t] = (hist[t] > 0) ? atomicAdd(&bcount[t], hist[t]) : 0;
  __syncthreads();
  for (int i = t; i < 256; i += 256) hist[i] = 0;
  __syncthreads();
  for (int i = t; i < nE; i += 256) {
    int b = rb[i];
    int r = atomicAdd(&hist[b], 1);
    int pos = base[b] + r;
    if (pos < BKT_CAP) buckets[(size_t)b * BKT_CAP + pos] = recs[i];
  }
}

// ---------------- Phase B: per-bucket counting sort (self-computed base) ----------
__global__ __launch_bounds__(256) void bucket_sort_kernel(
    const uint* __restrict__ buckets, const int* __restrict__ bcount,
    int* __restrict__ row_ptr, int* __restrict__ src_sorted, int N, int E, int NB) {
  const int b = blockIdx.x;
  const int t = threadIdx.x;
  __shared__ int h[512], o[512], c[512];
  __shared__ int wsum[4];
  __shared__ int gbase_sh;

  // exclusive prefix of bcount up to b (reuse h[0..255] as scratch)
  {
    int x = (t < NB) ? bcount[t] : 0;
    h[t] = x;
    __syncthreads();
    #pragma unroll
    for (int off = 1; off < 256; off <<= 1) {
      int v = (t >= off) ? h[t - off] : 0;
      __syncthreads();
      h[t] += v;
      __syncthreads();
    }
    if (t == 0) {
      gbase_sh = h[b] - bcount[b];
      if (b == 0) row_ptr[N] = E;
    }
    __syncthreads();
  }
  const int cnt = min(bcount[b], BKT_CAP);
  const int gbase = gbase_sh;
  const uint* rec = buckets + (size_t)b * BKT_CAP;

  for (int i = t; i < 512; i += 256) { h[i] = 0; c[i] = 0; }
  __syncthreads();
  for (int i = t; i < cnt; i += 256) atomicAdd(&h[rec[i] & 511], 1);
  __syncthreads();

  int a0 = h[2 * t], a1 = h[2 * t + 1];
  int s2 = a0 + a1;
  int lane = t & 63, w = t >> 6;
  int v = s2;
  #pragma unroll
  for (int off = 1; off < 64; off <<= 1) {
    int u = __shfl_up(v, off, 64);
    if (lane >= off) v += u;
  }
  if (lane == 63) wsum[w] = v;
  __syncthreads();
  int woff = 0;
  for (int i = 0; i < w; ++i) woff += wsum[i];
  int excl = (v - s2) + woff;
  o[2 * t]     = excl;
  o[2 * t + 1] = excl + a0;
  __syncthreads();

  for (int i = t; i < 512; i += 256) {
    int node = (b << 9) + i;
    if (node < N) row_ptr[node] = gbase + o[i];
  }
  for (int i = t; i < cnt; i += 256) {
    uint r = rec[i];
    int d9 = r & 511;
    int rk = atomicAdd(&c[d9], 1);
    src_sorted[gbase + o[d9] + rk] = (int)(r >> 9);
  }
}

// ---------------- MFMA GEMM + fused alpha epilogue (layers 1-3) ----------------
template <bool ABF16, int ALPHA>
__global__ __launch_bounds__(256) void mfma_gemm_kernel(const void* __restrict__ Av,
                                                        const ushort* __restrict__ Wt,
                                                        void* __restrict__ Cv, int n,
                                                        const float* __restrict__ asv,
                                                        const float* __restrict__ adv,
                                                        float* __restrict__ alpha_s,
                                                        float* __restrict__ alpha_d) {
  constexpr int TN = 128;
  constexpr int FI = 4;
  constexpr int FJ = 4;
  __shared__ char lds[32768 + 32768];
  ushort* sA = (ushort*)lds;
  ushort* sW = (ushort*)(lds + 32768);

  const int t = threadIdx.x;
  const int row0 = blockIdx.x * 128;
  const int lane = t & 63;
  const int wid = t >> 6;
  const int wr = wid >> 1, wc = wid & 1;

  float4 vd0, vd1;
  if constexpr (ALPHA == 2) {
    vd0 = ((const float4*)adv)[(t & 15) * 2];
    vd1 = ((const float4*)adv)[(t & 15) * 2 + 1];
  }

  #pragma unroll
  for (int i = 0; i < 8; ++i) {
    int r = i * 16 + (t >> 4);
    int c = t & 15;
    int gr = row0 + r;
    ushort8 o = 0;
    if (ABF16) {
      const ushort* Ab = (const ushort*)Av;
      if (gr < n) o = *(const ushort8*)(Ab + (size_t)gr * 128 + c * 8);
    } else {
      const float* A = (const float*)Av;
      float4 v0 = make_float4(0.f, 0.f, 0.f, 0.f), v1 = v0;
      if (gr < n) {
        const float4* Ar = (const float4*)(A + (size_t)gr * 128);
        v0 = Ar[c * 2];
        v1 = Ar[c * 2 + 1];
      }
      if constexpr (ALPHA == 2) {
        float pd = v0.x * vd0.x + v0.y * vd0.y + v0.z * vd0.z + v0.w * vd0.w
                 + v1.x * vd1.x + v1.y * vd1.y + v1.z * vd1.z + v1.w * vd1.w;
        pd += __shfl_xor(pd, 1, 64);
        pd += __shfl_xor(pd, 2, 64);
        pd += __shfl_xor(pd, 4, 64);
        pd += __shfl_xor(pd, 8, 64);
        if ((t & 15) == 0 && gr < n) alpha_d[gr] = pd;
      }
      o[0] = f2bf_rne(v0.x); o[1] = f2bf_rne(v0.y); o[2] = f2bf_rne(v0.z); o[3] = f2bf_rne(v0.w);
      o[4] = f2bf_rne(v1.x); o[5] = f2bf_rne(v1.y); o[6] = f2bf_rne(v1.z); o[7] = f2bf_rne(v1.w);
    }
    *(ushort8*)(sA + r * 128 + ((c ^ (r & 7)) * 8)) = o;
  }
  #pragma unroll
  for (int i = 0; i < 8; ++i) {
    int chunk = i * 256 + t;
    *(ushort8*)(sW + chunk * 8) = *(const ushort8*)(Wt + chunk * 8);
  }
  __syncthreads();

  f32x4 acc[FI][FJ] = {};
  const int lm = lane & 15, q = lane >> 4, l7 = lane & 7;

  #pragma unroll
  for (int kk = 0; kk < 4; ++kk) {
    const int cs = kk * 4 + q;
    short8 af[FI], bfr[FJ];
    #pragma unroll
    for (int i = 0; i < FI; ++i) {
      int r = wr * 64 + i * 16 + lm;
      af[i] = *(const short8*)(sA + r * 128 + ((cs ^ l7) * 8));
    }
    #pragma unroll
    for (int j = 0; j < FJ; ++j) {
      int nn = wc * 64 + j * 16 + lm;
      bfr[j] = *(const short8*)(sW + nn * 128 + ((cs ^ l7) * 8));
    }
    #pragma unroll
    for (int i = 0; i < FI; ++i)
      #pragma unroll
      for (int j = 0; j < FJ; ++j)
        acc[i][j] = __builtin_amdgcn_mfma_f32_16x16x32_bf16(af[i], bfr[j], acc[i][j], 0, 0, 0);
  }

  #pragma unroll
  for (int i = 0; i < FI; ++i) {
    #pragma unroll
    for (int j = 0; j < FJ; ++j) {
      int gcol = wc * 64 + j * 16 + lm;
      #pragma unroll
      for (int r = 0; r < 4; ++r) {
        int grow = row0 + wr * 64 + i * 16 + q * 4 + r;
        if (grow < n)
          ((ushort*)Cv)[(size_t)grow * TN + gcol] = f2bf_rne(acc[i][j][r]);
      }
    }
  }

  // ---- fused alpha epilogue ----
  __syncthreads();
  float* srs = (float*)lds;
  float* srd = (float*)lds + 256;
  float asl[FJ], adl[FJ];
  #pragma unroll
  for (int j = 0; j < FJ; ++j) {
    int gcol = wc * 64 + j * 16 + lm;
    asl[j] = asv[gcol];
    if constexpr (ALPHA == 1) adl[j] = adv[gcol];
  }
  #pragma unroll
  for (int i = 0; i < FI; ++i) {
    #pragma unroll
    for (int r = 0; r < 4; ++r) {
      float ps = 0.f, pdp = 0.f;
      #pragma unroll
      for (int j = 0; j < FJ; ++j) {
        ps = fmaf(acc[i][j][r], asl[j], ps);
        if constexpr (ALPHA == 1) pdp = fmaf(acc[i][j][r], adl[j], pdp);
      }
      ps += __shfl_xor(ps, 1, 64); ps += __shfl_xor(ps, 2, 64);
      ps += __shfl_xor(ps, 4, 64); ps += __shfl_xor(ps, 8, 64);
      if constexpr (ALPHA == 1) {
        pdp += __shfl_xor(pdp, 1, 64); pdp += __shfl_xor(pdp, 2, 64);
        pdp += __shfl_xor(pdp, 4, 64); pdp += __shfl_xor(pdp, 8, 64);
      }
      if (lm == 0) {
        int rl = wr * 64 + i * 16 + q * 4 + r;
        srs[rl * 2 + wc] = ps;
        if constexpr (ALPHA == 1) srd[rl * 2 + wc] = pdp;
      }
    }
  }
  __syncthreads();
  if (t < 128) {
    int grow = row0 + t;
    if (grow < n) {
      alpha_s[grow] = srs[t * 2] + srs[t * 2 + 1];
      if constexpr (ALPHA == 1) alpha_d[grow] = srd[t * 2] + srd[t * 2 + 1];
    }
  }
}

// ---------------- fused MLP head: out = relu(Pb@Wl1+bl1)@Wl2+bl2 ----------------
__global__ __launch_bounds__(256) void head_fused_kernel(
    const uint* __restrict__ Pb, const ushort* __restrict__ Wtl1,
    const float* __restrict__ bl1, const ushort* __restrict__ Wtl2,
    const float* __restrict__ bl2, float* __restrict__ out, int n) {
  __shared__ char lds[32768 + 32768];
  ushort* sA = (ushort*)lds;
  ushort* sW = (ushort*)(lds + 32768);
  const int t = threadIdx.x;
  const int row0 = blockIdx.x * 128;
  const int lane = t & 63, wid = t >> 6;
  const int wr = wid >> 1, wc = wid & 1;
  const int lm = lane & 15, q = lane >> 4, l7 = lane & 7;

  #pragma unroll
  for (int i = 0; i < 8; ++i) {
    int r = i * 16 + (t >> 4);
    int c = t & 15;
    int gr = row0 + r;
    ushort8 o = 0;
    if (gr < n) o = *(const ushort8*)((const ushort*)Pb + (size_t)gr * 128 + c * 8);
    *(ushort8*)(sA + r * 128 + ((c ^ (r & 7)) * 8)) = o;
  }
  #pragma unroll
  for (int i = 0; i < 8; ++i) {
    int chunk = i * 256 + t;
    *(ushort8*)(sW + chunk * 8) = *(const ushort8*)(Wtl1 + chunk * 8);
  }
  __syncthreads();

  f32x4 acc[4][4] = {};
  #pragma unroll
  for (int kk = 0; kk < 4; ++kk) {
    const int cs = kk * 4 + q;
    short8 af[4], bfr[4];
    #pragma unroll
    for (int i = 0; i < 4; ++i) {
      int r = wr * 64 + i * 16 + lm;
      af[i] = *(const short8*)(sA + r * 128 + ((cs ^ l7) * 8));
    }
    #pragma unroll
    for (int j = 0; j < 4; ++j) {
      int nn = wc * 64 + j * 16 + lm;
      bfr[j] = *(const short8*)(sW + nn * 128 + ((cs ^ l7) * 8));
    }
    #pragma unroll
    for (int i = 0; i < 4; ++i)
      #pragma unroll
      for (int j = 0; j < 4; ++j)
        acc[i][j] = __builtin_amdgcn_mfma_f32_16x16x32_bf16(af[i], bfr[j], acc[i][j], 0, 0, 0);
  }
  __syncthreads();

  #pragma unroll
  for (int i = 0; i < 4; ++i) {
    #pragma unroll
    for (int j = 0; j < 4; ++j) {
      int col = wc * 64 + j * 16 + lm;
      float bv = bl1[col];
      #pragma unroll
      for (int r = 0; r < 4; ++r) {
        int row = wr * 64 + i * 16 + q * 4 + r;
        float v = fmaxf(acc[i][j][r] + bv, 0.f);
        sA[row * 128 + (((col >> 3) ^ (row & 7)) * 8) + (col & 7)] = f2bf_rne(v);
      }
    }
  }
  #pragma unroll
  for (int i = 0; i < 4; ++i) {
    int chunk = i * 256 + t;
    *(ushort8*)(sW + chunk * 8) = *(const ushort8*)(Wtl2 + chunk * 8);
  }
  __syncthreads();

  f32x4 acc2[4][2] = {};
  #pragma unroll
  for (int kk = 0; kk < 4; ++kk) {
    const int cs = kk * 4 + q;
    short8 af[4], bfr[2];
    #pragma unroll
    for (int i = 0; i < 4; ++i) {
      int r = wr * 64 + i * 16 + lm;
      af[i] = *(const short8*)(sA + r * 128 + ((cs ^ l7) * 8));
    }
    #pragma unroll
    for (int j = 0; j < 2; ++j) {
      int nn = wc * 32 + j * 16 + lm;
      bfr[j] = *(const short8*)(sW + nn * 128 + ((cs ^ l7) * 8));
    }
    #pragma unroll
    for (int i = 0; i < 4; ++i)
      #pragma unroll
      for (int j = 0; j < 2; ++j)
        acc2[i][j] = __builtin_amdgcn_mfma_f32_16x16x32_bf16(af[i], bfr[j], acc2[i][j], 0, 0, 0);
  }
  #pragma unroll
  for (int i = 0; i < 4; ++i) {
    #pragma unroll
    for (int j = 0; j < 2; ++j) {
      int gcol = wc * 32 + j * 16 + lm;
      float bv = bl2[gcol];
      #pragma unroll
      for (int r = 0; r < 4; ++r) {
        int grow = row0 + wr * 64 + i * 16 + q * 4 + r;
        if (grow < n) out[(size_t)grow * 64 + gcol] = acc2[i][j][r] + bv;
      }
    }
  }
}

// ---------------- per-edge records: erec[j] = (src, exp(lrelu(as+ad))) ----------------
__global__ void edge_p_kernel(const int* __restrict__ row_ptr, const int* __restrict__ src_sorted,
                              const float* __restrict__ alpha_s, const float* __restrict__ alpha_d,
                              uint2* __restrict__ erec, int n) {
  int wid = blockIdx.x * (blockDim.x >> 6) + (threadIdx.x >> 6);
  int lane = threadIdx.x & 63;
  int node = wid * 4 + (lane >> 4);
  if (node >= n) return;
  int beg = row_ptr[node], end = row_ptr[node + 1];
  float ad = alpha_d[node];
  for (int j = beg + (lane & 15); j < end; j += 16) {
    int u = src_sorted[j];
    float e = alpha_s[u] + ad;
    e = (e > 0.f) ? e : 0.2f * e;
    erec[j] = make_uint2((uint)u, __float_as_uint(__expf(e)));
  }
}

// ---------------- GAT aggregation: 2 nodes/wave, 8 edges in flight ----------
__global__ void gat_aggregate_kernel(const uint2* __restrict__ hs2,
                                     const uint2* __restrict__ erec,
                                     const int* __restrict__ row_ptr,
                                     const float* __restrict__ bias,
                                     uint2* __restrict__ outb, int n) {
  const int t = threadIdx.x;
  const int pairw = blockIdx.x * 4 + (t >> 6);
  const int lane = t & 63;
  const int half = lane >> 5;
  const int sl = lane & 31;
  const int node = pairw * 2 + half;
  const bool active = node < n;
  const int beg = active ? row_ptr[node] : 0;
  const int end = active ? row_ptr[node + 1] : 0;

  float sA = 0.f, sB = 0.f, sC = 0.f, sD = 0.f;
  float Ax0 = 0.f, Ay0 = 0.f, Ax1 = 0.f, Ay1 = 0.f;
  float Bx0 = 0.f, By0 = 0.f, Bx1 = 0.f, By1 = 0.f;
  float Cx0 = 0.f, Cy0 = 0.f, Cx1 = 0.f, Cy1 = 0.f;
  float Dx0 = 0.f, Dy0 = 0.f, Dx1 = 0.f, Dy1 = 0.f;

  int j = beg;
  for (; j + 8 <= end; j += 8) {
    uint4 eA = *(const uint4*)&erec[j];
    uint4 eB = *(const uint4*)&erec[j + 2];
    uint4 eC = *(const uint4*)&erec[j + 4];
    uint4 eD = *(const uint4*)&erec[j + 6];
    uint2 h0 = hs2[(size_t)eA.x * 32 + sl];
    uint2 h1 = hs2[(size_t)eA.z * 32 + sl];
    uint2 h2 = hs2[(size_t)eB.x * 32 + sl];
    uint2 h3 = hs2[(size_t)eB.z * 32 + sl];
    uint2 h4 = hs2[(size_t)eC.x * 32 + sl];
    uint2 h5 = hs2[(size_t)eC.z * 32 + sl];
    uint2 h6 = hs2[(size_t)eD.x * 32 + sl];
    uint2 h7 = hs2[(size_t)eD.z * 32 + sl];
    float p0 = __uint_as_float(eA.y), p1 = __uint_as_float(eA.w);
    float p2 = __uint_as_float(eB.y), p3 = __uint_as_float(eB.w);
    float p4 = __uint_as_float(eC.y), p5 = __uint_as_float(eC.w);
    float p6 = __uint_as_float(eD.y), p7 = __uint_as_float(eD.w);
    sA += p0 + p1; sB += p2 + p3; sC += p4 + p5; sD += p6 + p7;
    acc4(Ax0, Ay0, Ax1, Ay1, p0, h0);
    acc4(Bx0, By0, Bx1, By1, p1, h1);
    acc4(Cx0, Cy0, Cx1, Cy1, p2, h2);
    acc4(Dx0, Dy0, Dx1, Dy1, p3, h3);
    acc4(Ax0, Ay0, Ax1, Ay1, p4, h4);
    acc4(Bx0, By0, Bx1, By1, p5, h5);
    acc4(Cx0, Cy0, Cx1, Cy1, p6, h6);
    acc4(Dx0, Dy0, Dx1, Dy1, p7, h7);
  }
  for (; j + 4 <= end; j += 4) {
    uint4 eA = *(const uint4*)&erec[j];
    uint4 eB = *(const uint4*)&erec[j + 2];
    uint2 h0 = hs2[(size_t)eA.x * 32 + sl];
    uint2 h1 = hs2[(size_t)eA.z * 32 + sl];
    uint2 h2 = hs2[(size_t)eB.x * 32 + sl];
    uint2 h3 = hs2[(size_t)eB.z * 32 + sl];
    float p0 = __uint_as_float(eA.y), p1 = __uint_as_float(eA.w);
    float p2 = __uint_as_float(eB.y), p3 = __uint_as_float(eB.w);
    sA += p0 + p1; sB += p2 + p3;
    acc4(Ax0, Ay0, Ax1, Ay1, p0, h0);
    acc4(Bx0, By0, Bx1, By1, p1, h1);
    acc4(Cx0, Cy0, Cx1, Cy1, p2, h2);
    acc4(Dx0, Dy0, Dx1, Dy1, p3, h3);
  }
  for (; j < end; ++j) {
    uint2 r = erec[j];
    float p = __uint_as_float(r.y);
    uint2 h = hs2[(size_t)r.x * 32 + sl];
    sA += p;
    acc4(Ax0, Ay0, Ax1, Ay1, p, h);
  }

  if (active) {
    float s = (sA + sB) + (sC + sD);
    float inv = 1.f / (s + 1e-16f);
    float4 bv = ((const float4*)bias)[sl];
    float o0 = fmaxf(fmaf((Ax0 + Bx0) + (Cx0 + Dx0), inv, bv.x), 0.f);
    float o1 = fmaxf(fmaf((Ay0 + By0) + (Cy0 + Dy0), inv, bv.y), 0.f);
    float o2 = fmaxf(fmaf((Ax1 + Bx1) + (Cx1 + Dx1), inv, bv.z), 0.f);
    float o3 = fmaxf(fmaf((Ay1 + By1) + (Cy1 + Dy1), inv, bv.w), 0.f);
    uint2 pk;
    pk.x = ((uint)f2bf_rne(o1) << 16) | (uint)f2bf_rne(o0);
    pk.y = ((uint)f2bf_rne(o3) << 16) | (uint)f2bf_rne(o2);
    outb[(size_t)node * 32 + sl] = pk;
  }
}

// ---------------------------------------------------------------------------
extern "C" void kernel_launch(void* const* d_in, const int* in_sizes, int n_in,
                              void* d_out, int out_size, void* d_ws, size_t ws_size,
                              hipStream_t stream) {
  const float* x     = (const float*)d_in[0];
  const int*   eidx  = (const int*)d_in[1];
  const float* W1s   = (const float*)d_in[2];
  const float* W1d   = (const float*)d_in[3];
  const float* a1s   = (const float*)d_in[4];
  const float* a1d   = (const float*)d_in[5];
  const float* b1    = (const float*)d_in[6];
  const float* W2    = (const float*)d_in[7];
  const float* a2s   = (const float*)d_in[8];
  const float* a2d   = (const float*)d_in[9];
  const float* b2    = (const float*)d_in[10];
  const float* W3    = (const float*)d_in[11];
  const float* a3s   = (const float*)d_in[12];
  const float* a3d   = (const float*)d_in[13];
  const float* b3    = (const float*)d_in[14];
  const float* Wl1   = (const float*)d_in[15];
  const float* bl1   = (const float*)d_in[16];
  const float* Wl2   = (const float*)d_in[17];
  const float* bl2   = (const float*)d_in[18];
  float* out = (float*)d_out;

  const int N = in_sizes[0] / 128;
  const int E = in_sizes[1] / 2;
  const int* src = eidx;
  const int* dst = eidx + E;
  const int NB = (N + 511) >> 9;

  // ---- workspace layout ----
  char* base = (char*)d_ws;
  size_t off = 0;
  auto alloc = [&](size_t bytes) -> void* {
    void* p = base + off;
    off += (bytes + 511) & ~(size_t)511;
    return p;
  };
  uint*  Pb       = (uint*)alloc((size_t)N * 128 * 2);   // layer io, packed bf16
  uint*  Qb       = (uint*)alloc((size_t)N * 128 * 2);   // messages, packed bf16
  char*  breg     = (char*)alloc((size_t)N * 128 * 4);   // buckets / erec region
  uint*  buckets  = (uint*)breg;                         // dead after CSR build
  uint2* erec     = (uint2*)(breg + ((size_t)24 << 20));
  float* alpha_s  = (float*)alloc((size_t)N * 4);
  float* alpha_d  = (float*)alloc((size_t)N * 4);
  float* vd       = (float*)alloc(128 * 4);
  int* row_ptr    = (int*)alloc((size_t)(N + 1) * 4);
  int* bcount     = (int*)alloc(256 * 4);
  int* src_sorted = (int*)alloc((size_t)E * 4);
  ushort* Wt1     = (ushort*)alloc(128 * 128 * 2);
  ushort* Wt2     = (ushort*)alloc(128 * 128 * 2);
  ushort* Wt3     = (ushort*)alloc(128 * 128 * 2);
  ushort* Wtl1    = (ushort*)alloc(128 * 128 * 2);
  ushort* Wtl2    = (ushort*)alloc(64 * 128 * 2);
  (void)ws_size;

  const int TB = 256;
  const int ggrid = (N + 127) / 128;
  const int pagrid = (E + PA_CHUNK - 1) / PA_CHUNK;
  const int epgrid = (N + 15) / 16;
  const int aggrid = (N + 7) / 8;

  // ---- CSR build + weight prep (scatter grid carries wprep/vd blocks) ----
  hipMemsetAsync(bcount, 0, 256 * 4, stream);
  bucket_scatter_kernel<<<pagrid + 68, 256, 0, stream>>>(
      src, dst, bcount, buckets, E, NB, pagrid,
      W1s, W2, W3, Wl1, Wl2, Wt1, Wt2, Wt3, Wtl1, Wtl2, W1d, a1d, vd);
  bucket_sort_kernel<<<NB, 256, 0, stream>>>(buckets, bcount, row_ptr, src_sorted, N, E, NB);

  // ---- layer 1: x -> Pb ----
  mfma_gemm_kernel<false, 2><<<ggrid, 256, 0, stream>>>(
      x, Wt1, Qb, N, a1s, vd, alpha_s, alpha_d);
  edge_p_kernel<<<epgrid, TB, 0, stream>>>(row_ptr, src_sorted, alpha_s, alpha_d, erec, N);
  gat_aggregate_kernel<<<aggrid, TB, 0, stream>>>((const uint2*)Qb, erec, row_ptr, b1, (uint2*)Pb, N);

  // ---- layer 2: Pb -> Pb ----
  mfma_gemm_kernel<true, 1><<<ggrid, 256, 0, stream>>>(
      Pb, Wt2, Qb, N, a2s, a2d, alpha_s, alpha_d);
  edge_p_kernel<<<epgrid, TB, 0, stream>>>(row_ptr, src_sorted, alpha_s, alpha_d, erec, N);
  gat_aggregate_kernel<<<aggrid, TB, 0, stream>>>((const uint2*)Qb, erec, row_ptr, b2, (uint2*)Pb, N);

  // ---- layer 3: Pb -> Pb ----
  mfma_gemm_kernel<true, 1><<<ggrid, 256, 0, stream>>>(
      Pb, Wt3, Qb, N, a3s, a3d, alpha_s, alpha_d);
  edge_p_kernel<<<epgrid, TB, 0, stream>>>(row_ptr, src_sorted, alpha_s, alpha_d, erec, N);
  gat_aggregate_kernel<<<aggrid, TB, 0, stream>>>((const uint2*)Qb, erec, row_ptr, b3, (uint2*)Pb, N);

  // ---- fused MLP head ----
  head_fused_kernel<<<ggrid, 256, 0, stream>>>(Pb, Wtl1, bl1, Wtl2, bl2, out, N);
}